// Round 6
// baseline (107.842 us; speedup 1.0000x reference)
//
#include <hip/hip_runtime.h>

// R16: time-budget re-derivation across R10/R12/R14/R15 pins: harness
// poison-fill ~44us (inside dur_us), mega ~33us, gather ~25us, overhead ~5us.
// R15's LDS-entry change was neutral -> entries were already scalar-loaded
// (readfirstlane-uniform -> s_load, lgkmcnt). Gather kept byte-identical.
// Mega's long pole theory: smax branch's float v[40] cannot fit in the
// measured VGPR_Count=36 -> scratch (120 round-trips/thread, 3 passes) on a
// 66-block branch with nothing to hide latency. Fix: 1.5-pass streaming
// smax (max -> reload+exp+sum -> reload+exp*inv+store), bitwise-identical
// op order, no local array, unroll 20/8/8. Branch order now smax, build,
// pack, zero (long poles dispatch first).
// Predict: mega 33 -> ~15, total 107.3 -> ~90. Neutral => smax wasn't the
// pole (spill hypothesis eliminated, target build/pack next).

constexpr int D = 40, H = 32, W = 88, HW = H * W;       // 2816
constexpr int C = 128, NCAM = 6;
constexpr int BEV = 125, NBINS = BEV * BEV;             // 15625
constexpr int NCOLS = NCAM * HW;                        // 16896

typedef __attribute__((ext_vector_type(8))) unsigned short us8;
typedef __attribute__((ext_vector_type(4))) float f4;
typedef __attribute__((ext_vector_type(2))) float f2;

__device__ __forceinline__ unsigned short f2bf(float x) {   // RNE
    unsigned u = __float_as_uint(x);
    return (unsigned short)((u + 0x7FFF + ((u >> 16) & 1)) >> 16);
}
__device__ __forceinline__ float b2f(unsigned short u) {
    return __uint_as_float(((unsigned)u) << 16);
}

// ---------------------------------------------------------------- constexpr tables
struct Tabs { short XP[D][126]; short YP[D][126]; };
constexpr Tabs make_tabs() {
    Tabs t{};
    for (int d = 0; d < D; ++d) {
        int dep = d + 2;
        int cntx[126] = {};
        for (int w = 0; w < W; ++w) {
            float gx = (float)(w * dep) / 3567.0f * 100.0f - 50.0f;
            int ix = (int)((gx + 50.0f) / 0.8f);
            if (ix < 125) cntx[ix]++;
        }
        t.XP[d][0] = 0;
        for (int X = 0; X < 125; ++X) t.XP[d][X + 1] = (short)(t.XP[d][X] + cntx[X]);
        int cnty[126] = {};
        for (int h = 0; h < H; ++h) {
            float gy = (float)(h * dep) / 1271.0f * 100.0f - 50.0f;
            int iy = (int)((gy + 50.0f) / 0.8f);
            if (iy < 125) cnty[iy]++;
        }
        t.YP[d][0] = 0;
        for (int Y = 0; Y < 125; ++Y) t.YP[d][Y + 1] = (short)(t.YP[d][Y] + cnty[Y]);
    }
    return t;
}
constexpr Tabs g_tabs = make_tabs();
__device__ const Tabs g_tab = g_tabs;                // device copy for build

// ---------------------------------------------------------------- constexpr segments
// a: iy<<16 | X0<<8 | X1 ; b(raw): split<<31 | d0<<25 | d1<<19 | count
struct SegTable { unsigned a[4096]; unsigned b[4096]; int n; };

constexpr SegTable make_segs() {
    SegTable S{};
    int ns = 0;
    for (int iy = 0; iy < 125; ++iy) {
        int cnt[125] = {};
        for (int d = 0; d < D; ++d) {
            int yc = g_tabs.YP[d][iy + 1] - g_tabs.YP[d][iy];
            if (yc == 0) continue;
            for (int X = 0; X < 125; ++X)
                cnt[X] += (g_tabs.XP[d][X + 1] - g_tabs.XP[d][X]) * yc;
        }
        int X = 0;
        while (X < 125) {
            if (cnt[X] > 176) {                      // lone heavy bin: d-split
                int d0 = 0;
                while (d0 < D) {
                    int run = 0, d1 = d0;
                    while (d1 < D) {
                        int piece = (g_tabs.XP[d1][X + 1] - g_tabs.XP[d1][X]) *
                                    (g_tabs.YP[d1][iy + 1] - g_tabs.YP[d1][iy]);
                        if (d1 > d0 && run + piece > 128) break;
                        run += piece; ++d1;
                    }
                    if (run > 0) {
                        S.a[ns] = ((unsigned)iy << 16) | ((unsigned)X << 8) | (unsigned)(X + 1);
                        S.b[ns] = (1u << 31) | ((unsigned)d0 << 25) | ((unsigned)d1 << 19) | (unsigned)run;
                        ++ns;
                    }
                    d0 = d1;
                }
                ++X;
            } else {
                int X0 = X, run = 0;
                while (X < 125 && (X - X0) < 16 && cnt[X] <= 176 &&
                       (X == X0 || run + cnt[X] <= 128)) {
                    run += cnt[X]; ++X;
                }
                if (run > 0) {
                    S.a[ns] = ((unsigned)iy << 16) | ((unsigned)X0 << 8) | (unsigned)X;
                    S.b[ns] = ((unsigned)0 << 25) | ((unsigned)D << 19) | (unsigned)run;
                    ++ns;
                }
            }
        }
    }
    S.n = ns;
    return S;
}
constexpr SegTable g_raw = make_segs();

constexpr SegTable reorder_segs() {                  // heavy-first, 2 passes
    SegTable R{};
    int pos = 0;
    for (int i = 0; i < g_raw.n; ++i)
        if ((int)(g_raw.b[i] & 0x7FFFF) >= 120) { R.a[pos] = g_raw.a[i]; R.b[pos] = g_raw.b[i]; ++pos; }
    for (int i = 0; i < g_raw.n; ++i)
        if ((int)(g_raw.b[i] & 0x7FFFF) <  120) { R.a[pos] = g_raw.a[i]; R.b[pos] = g_raw.b[i]; ++pos; }
    R.n = pos;
    return R;
}
constexpr SegTable g_ct = reorder_segs();
constexpr int NSEG = g_ct.n;
static_assert(NSEG > 0 && NSEG <= 4096, "seg table overflow");
__device__ const SegTable g_segs = g_ct;

// ---------------------------------------------------------------- constexpr meta
// meta: split<<31 | start<<10 | ngroups. Wave dg's entries live at
// glist[start + dg*ng*4 .. +ng*4). Cheap prefix pass (~20K constexpr steps).
struct Meta { unsigned m[4096]; int ne; };
constexpr Meta make_meta() {
    Meta M{};
    int pos = 0;
    for (int i = 0; i < NSEG; ++i) {
        int cnt = (int)(g_ct.b[i] & 0x7FFFF);
        int ng = (((cnt + 1) >> 1) + 3) >> 2;        // groups of 4 per wave
        M.m[i] = (g_ct.b[i] & 0x80000000u) | ((unsigned)pos << 10) | (unsigned)ng;
        pos += 2 * ng * 4;
    }
    M.ne = pos;
    return M;
}
constexpr Meta g_mt = make_meta();
constexpr int NE_TOT = g_mt.ne;
static_assert(NE_TOT < (1 << 21), "start field overflow");
struct MetaArr { unsigned m[4096]; };
constexpr MetaArr make_meta_arr() { MetaArr A{}; for (int i = 0; i < 4096; ++i) A.m[i] = g_mt.m[i]; return A; }
__device__ const MetaArr g_metaD = make_meta_arr();

// entry: flush<<31 | bl<<19 | d<<12 | hw  (bl=16 -> LDS trash row; dummies pad
// each wave's list to a multiple of 4). Built on device each launch.
__device__ __align__(16) unsigned g_glist[NE_TOT + 64];

// ---------------------------------------------------------------- D1: mega
constexpr int SMAX_BLOCKS  = NCOLS / 256;           // 66
constexpr int BUILD_BLOCKS = (NSEG + 3) / 4;        // one WAVE per segment
constexpr int PACK_BLOCKS  = (C / 8) * (HW / 32);   // 1408
constexpr int ZERO_TOTAL   = C * NBINS / 4;         // 500000 f4
constexpr int ZERO_BLOCKS  = (ZERO_TOTAL + 1023) / 1024;  // 489
constexpr int MEGA_BLOCKS  = SMAX_BLOCKS + BUILD_BLOCKS + PACK_BLOCKS + ZERO_BLOCKS;

__global__ void __launch_bounds__(256) mega_kernel(
        const float* __restrict__ feat,     // [NCAM][C][HW]
        const float* __restrict__ logits,   // [NCAM][D][HW]
        float* __restrict__ probs_t,
        unsigned short* __restrict__ feat_p,
        float* __restrict__ out) {
    __shared__ __align__(16) float tile[NCAM * 8 * 37];
    int b = blockIdx.x, t = threadIdx.x;

    if (b < SMAX_BLOCKS) {
        // -------- softmax over D, 1.5-pass streaming (no local array, no
        // spill). Bitwise-identical op order to the v[40] version.
        int col = b * 256 + t;                       // < NCOLS exact
        int n  = col / HW;
        int hw = col - n * HW;
        const float* src = logits + ((size_t)n * D) * HW + hw;
        float m = -3.402823466e+38f;
#pragma unroll 20
        for (int d = 0; d < D; ++d)
            m = fmaxf(m, src[(size_t)d * HW]);
        float s = 0.f;
#pragma unroll 8
        for (int d = 0; d < D; ++d)
            s += expf(src[(size_t)d * HW] - m);
        float inv = 1.0f / s;
#pragma unroll 8
        for (int d = 0; d < D; ++d)
            probs_t[(size_t)((d << 12) | hw) * 8 + n] =
                expf(src[(size_t)d * HW] - m) * inv;

    } else if (b < SMAX_BLOCKS + BUILD_BLOCKS) {
        // -------- point-list build: one wave per segment, lane = depth cell.
        int slot = (b - SMAX_BLOCKS) * 4 + (t >> 6);
        int lane = t & 63;
        if (slot < NSEG) {
            unsigned da = g_segs.a[slot], db = g_segs.b[slot], mb = g_metaD.m[slot];
            int iy = (int)(da >> 16), X0 = (int)((da >> 8) & 0xFF), X1 = (int)(da & 0xFF);
            int d0 = (int)((db >> 25) & 0x3F), d1 = (int)((db >> 19) & 0x3F);
            int drange = d1 - d0;                    // <= 40 <= 64 lanes
            int ng4 = (int)(mb & 0x3FFu) * 4;
            unsigned* gl = g_glist + ((mb >> 10) & 0x1FFFFFu);
            int base = 0;
            for (int bl = 0; bl < X1 - X0; ++bl) {   // all cells of bl in ONE pass
                int d = d0 + lane;
                int hb = 0, he = 0, wb = 0, we = 0, cnt = 0;
                if (lane < drange) {
                    hb = g_tab.YP[d][iy];      he = g_tab.YP[d][iy + 1];
                    wb = g_tab.XP[d][X0 + bl]; we = g_tab.XP[d][X0 + bl + 1];
                    cnt = (he - hb) * (we - wb);
                }
                int inc = cnt;                       // inclusive wave scan
#pragma unroll
                for (int delta = 1; delta < 64; delta <<= 1) {
                    int y = __shfl_up(inc, delta, 64);
                    if (lane >= delta) inc += y;
                }
                int tot = __shfl(inc, 63, 64);
                int o = base + inc - cnt;            // this lane's first ordinal
                int run_end = base + tot;            // end of this bl-run
                for (int h = hb; h < he; ++h)
                    for (int w = wb; w < we; ++w) {
                        unsigned v = ((unsigned)bl << 19) | ((unsigned)d << 12)
                                   | (unsigned)(h * W + w);
                        // last two ordinals of the run == last-per-parity -> flush
                        if (o >= run_end - 2) v |= 0x80000000u;
                        gl[(o & 1) * ng4 + (o >> 1)] = v;
                        ++o;
                    }
                base = run_end;
            }
            int m = base;                            // pad with trash-row dummies
#pragma unroll
            for (int dg = 0; dg < 2; ++dg) {
                int cnt2 = (m + 1 - dg) >> 1;
                for (int k = cnt2 + lane; k < ng4; k += 64)
                    gl[dg * ng4 + k] = (16u << 19) | 0x80000000u;
            }
        }

    } else if (b < SMAX_BLOCKS + BUILD_BLOCKS + PACK_BLOCKS) {
        int bb = b - SMAX_BLOCKS - BUILD_BLOCKS;
        int c0  = (bb / 88) * 8;
        int hw0 = (bb % 88) * 32;
        int cq = t >> 5, hwL = t & 31;
#pragma unroll
        for (int n = 0; n < NCAM; ++n)
            tile[(n * 8 + cq) * 37 + hwL] =
                feat[((size_t)(n * C + c0 + cq)) * HW + hw0 + hwL];
        __syncthreads();
        int hl = t >> 3, cL = t & 7;
        us8 v;
#pragma unroll
        for (int n = 0; n < NCAM; ++n)
            v[n] = f2bf(tile[(n * 8 + cL) * 37 + hl]);
        v[6] = 0; v[7] = 0;
        *(us8*)(feat_p + ((size_t)(hw0 + hl) * C + (c0 + cL)) * 8) = v;

    } else {
        int base = (b - SMAX_BLOCKS - BUILD_BLOCKS - PACK_BLOCKS) * 1024;
#pragma unroll
        for (int k = 0; k < 4; ++k) {
            int i = base + k * 256 + t;
            if (i < ZERO_TOTAL) ((f4*)out)[i] = f4{0.f, 0.f, 0.f, 0.f};
        }
    }
}

// ---------------------------------------------------------------- D2: gather
// (byte-identical to R15) Grid = NSEG*2, 128 thr = 2 waves; lane = channel
// within chalf. Entries preloaded to LDS; unconditional double-buffered
// groups of 4; uniform flush branch from precomputed flush bits.
__global__ void __launch_bounds__(128, 4) gather_kernel(
        const unsigned short* __restrict__ feat_p,   // [hw][c][8] bf16
        const float* __restrict__ probs_t,           // [(d<<12)|hw][8] f32
        float* __restrict__ out) {                   // [C][NBINS]
    __shared__ __align__(16) float T[2][17][66];     // 8976 B, row 16 = trash
    __shared__ __align__(16) unsigned EL[192];       // entry list (<=176 used)
    int t = threadIdx.x;
    int slot = blockIdx.x >> 1, chalf = blockIdx.x & 1;
    unsigned da = g_segs.a[slot], mb = g_metaD.m[slot];
    int iy = (int)(da >> 16), X0 = (int)((da >> 8) & 0xFF), X1 = (int)(da & 0xFF);
    int width = X1 - X0;
    bool split = (mb >> 31) != 0;
    int ng = (int)(mb & 0x3FFu);
    unsigned start = (mb >> 10) & 0x1FFFFFu;
    int dg = __builtin_amdgcn_readfirstlane((int)(threadIdx.x >> 6));
    int lane = t & 63;
    int c = chalf * 64 + lane;
    int ntot = ng * 8;                               // both waves' entry words

    if (t < ntot) EL[t] = g_glist[start + (unsigned)t];          // <=176
    if (t + 128 < ntot) EL[t + 128] = g_glist[start + (unsigned)(t + 128)];
    { float* Tf = &T[0][0][0];
      for (int i = t; i < 2 * 17 * 66; i += 128) Tf[i] = 0.f; }
    __syncthreads();

    const unsigned* ep = EL + dg * ng * 4;           // LDS pointer, 16B aligned
    const unsigned short* fbase = feat_p + (size_t)c * 8;
    float* Tp = &T[dg][0][0];
    float racc = 0.f;

#define LOADE(E, g_) { uint4 ee_ = *(const uint4*)(ep + 4 * (g_));            \
    E[0] = (unsigned)__builtin_amdgcn_readfirstlane((int)ee_.x);              \
    E[1] = (unsigned)__builtin_amdgcn_readfirstlane((int)ee_.y);              \
    E[2] = (unsigned)__builtin_amdgcn_readfirstlane((int)ee_.z);              \
    E[3] = (unsigned)__builtin_amdgcn_readfirstlane((int)ee_.w); }
#define ISSUE(S, E) _Pragma("unroll") for (int i_ = 0; i_ < 4; ++i_) {        \
    fv##S[i_] = *(const us8*)(fbase + ((size_t)(E[i_] & 0xFFFu) << 10));      \
    const float* pp_ = probs_t + ((size_t)(E[i_] & 0x3FFFFu) << 3);           \
    pa##S[i_] = *(const f4*)pp_; pb##S[i_] = *(const f2*)(pp_ + 4); }
#define CONS(S, E) _Pragma("unroll") for (int i_ = 0; i_ < 4; ++i_) {         \
    racc += pa##S[i_].x * b2f(fv##S[i_][0]) + pa##S[i_].y * b2f(fv##S[i_][1]) \
          + pa##S[i_].z * b2f(fv##S[i_][2]) + pa##S[i_].w * b2f(fv##S[i_][3]) \
          + pb##S[i_].x * b2f(fv##S[i_][4]) + pb##S[i_].y * b2f(fv##S[i_][5]);\
    if (E[i_] & 0x80000000u) {                                                \
        Tp[((E[i_] >> 19) & 31u) * 66 + (unsigned)lane] += racc; racc = 0.f; } }

    unsigned EA[4], EB[4], ET[4];
    us8 fvA[4], fvB[4];
    f4 paA[4], paB[4];
    f2 pbA[4], pbB[4];
    LOADE(EA, 0); LOADE(EB, 1);                      // overshoot stays in EL[192]
    ISSUE(A, EA);
    int g = 0;
    for (; g + 2 <= ng; g += 2) {
        ISSUE(B, EB);                                // data loads for group g+1
        LOADE(ET, g + 2);                            // LDS read (lgkmcnt only)
        CONS(A, EA);                                 // consume group g
        if (g + 2 < ng) {
            ISSUE(A, ET);                            // data loads for group g+2
#pragma unroll
            for (int q = 0; q < 4; ++q) EA[q] = ET[q];
        }
        CONS(B, EB);                                 // consume group g+1
        LOADE(EB, g + 3);                            // entries for next ISSUE(B)
    }
    if (g < ng) CONS(A, EA);                         // odd-ng tail (already issued)
#undef LOADE
#undef ISSUE
#undef CONS
    __syncthreads();

    int binbase = iy * BEV + X0;
#pragma unroll
    for (int it = 0; it < 8; ++it) {                 // 16 bl x 8 cc per iter
        int bl = t & 15, cc = it * 8 + (t >> 4);     // cc in [0,64)
        if (bl < width) {
            float v = T[0][bl][cc] + T[1][bl][cc];
            float* dst = &out[(size_t)(chalf * 64 + cc) * NBINS + binbase + bl];
            if (split) atomicAdd(dst, v);
            else       *dst = v;
        }
    }
}

// ---------------------------------------------------------------- launch
extern "C" void kernel_launch(void* const* d_in, const int* in_sizes, int n_in,
                              void* d_out, int out_size, void* d_ws, size_t ws_size,
                              hipStream_t stream) {
    const float* img_feat     = (const float*)d_in[0];
    const float* depth_logits = (const float*)d_in[1];
    float* out = (float*)d_out;

    char* p = (char*)d_ws;
    float*          probs_t = (float*)p;          p += (size_t)D * 4096 * 8 * 4;  // 5.24 MB
    unsigned short* feat_p  = (unsigned short*)p; p += (size_t)HW * C * 8 * 2;    // 5.77 MB

    mega_kernel<<<MEGA_BLOCKS, 256, 0, stream>>>(
        img_feat, depth_logits, probs_t, feat_p, out);
    gather_kernel<<<NSEG * 2, 128, 0, stream>>>(feat_p, probs_t, out);
}

// Round 7
// 106.254 us; speedup vs baseline: 1.0149x; 1.0149x over previous
//
#include <hip/hip_runtime.h>

// R17: two neutral mega rounds (R15 LDS-entries, R16 streaming-smax) =>
// mega theories weak; all budget models agree gather ~20-25us vs ~3us floor,
// traffic-accountable: 110K pts x (1KB feat line-traffic + 64B probs) x 2
// chalf ~= 227MB through L2/LLC @ ~9.5TB/s ~= 23us -> BW-bound + possible
// latency residue (only ~12 loads in flight). This round, gather-only
// (entry format/build/meta untouched):
//  1) 12B feat pack: feat_p [hw][c][6] shorts (drop 2 pad cams): 16->12
//     lines/point/wave (-23% traffic); loads 3x dword (4B-aligned always);
//     bf16 extract via shift/mask (bit-identical values).
//  2) depth-3 pipeline A/B/C: ~60 loads in flight (vmcnt queue is 64);
//     launch_bounds(128,2) so ~150 VGPR doesn't spill (grid is 4 blk/CU).
// Predict: gather -> ~15-17us, VGPR ~140-160, total ~97-102, absmax same.
// Neutral => pivot to dispatch-overhead (cooperative merge) next.

constexpr int D = 40, H = 32, W = 88, HW = H * W;       // 2816
constexpr int C = 128, NCAM = 6;
constexpr int BEV = 125, NBINS = BEV * BEV;             // 15625
constexpr int NCOLS = NCAM * HW;                        // 16896

typedef __attribute__((ext_vector_type(8))) unsigned short us8;
typedef __attribute__((ext_vector_type(4))) float f4;
typedef __attribute__((ext_vector_type(2))) float f2;

__device__ __forceinline__ unsigned short f2bf(float x) {   // RNE
    unsigned u = __float_as_uint(x);
    return (unsigned short)((u + 0x7FFF + ((u >> 16) & 1)) >> 16);
}

// ---------------------------------------------------------------- constexpr tables
struct Tabs { short XP[D][126]; short YP[D][126]; };
constexpr Tabs make_tabs() {
    Tabs t{};
    for (int d = 0; d < D; ++d) {
        int dep = d + 2;
        int cntx[126] = {};
        for (int w = 0; w < W; ++w) {
            float gx = (float)(w * dep) / 3567.0f * 100.0f - 50.0f;
            int ix = (int)((gx + 50.0f) / 0.8f);
            if (ix < 125) cntx[ix]++;
        }
        t.XP[d][0] = 0;
        for (int X = 0; X < 125; ++X) t.XP[d][X + 1] = (short)(t.XP[d][X] + cntx[X]);
        int cnty[126] = {};
        for (int h = 0; h < H; ++h) {
            float gy = (float)(h * dep) / 1271.0f * 100.0f - 50.0f;
            int iy = (int)((gy + 50.0f) / 0.8f);
            if (iy < 125) cnty[iy]++;
        }
        t.YP[d][0] = 0;
        for (int Y = 0; Y < 125; ++Y) t.YP[d][Y + 1] = (short)(t.YP[d][Y] + cnty[Y]);
    }
    return t;
}
constexpr Tabs g_tabs = make_tabs();
__device__ const Tabs g_tab = g_tabs;                // device copy for build

// ---------------------------------------------------------------- constexpr segments
// a: iy<<16 | X0<<8 | X1 ; b(raw): split<<31 | d0<<25 | d1<<19 | count
struct SegTable { unsigned a[4096]; unsigned b[4096]; int n; };

constexpr SegTable make_segs() {
    SegTable S{};
    int ns = 0;
    for (int iy = 0; iy < 125; ++iy) {
        int cnt[125] = {};
        for (int d = 0; d < D; ++d) {
            int yc = g_tabs.YP[d][iy + 1] - g_tabs.YP[d][iy];
            if (yc == 0) continue;
            for (int X = 0; X < 125; ++X)
                cnt[X] += (g_tabs.XP[d][X + 1] - g_tabs.XP[d][X]) * yc;
        }
        int X = 0;
        while (X < 125) {
            if (cnt[X] > 176) {                      // lone heavy bin: d-split
                int d0 = 0;
                while (d0 < D) {
                    int run = 0, d1 = d0;
                    while (d1 < D) {
                        int piece = (g_tabs.XP[d1][X + 1] - g_tabs.XP[d1][X]) *
                                    (g_tabs.YP[d1][iy + 1] - g_tabs.YP[d1][iy]);
                        if (d1 > d0 && run + piece > 128) break;
                        run += piece; ++d1;
                    }
                    if (run > 0) {
                        S.a[ns] = ((unsigned)iy << 16) | ((unsigned)X << 8) | (unsigned)(X + 1);
                        S.b[ns] = (1u << 31) | ((unsigned)d0 << 25) | ((unsigned)d1 << 19) | (unsigned)run;
                        ++ns;
                    }
                    d0 = d1;
                }
                ++X;
            } else {
                int X0 = X, run = 0;
                while (X < 125 && (X - X0) < 16 && cnt[X] <= 176 &&
                       (X == X0 || run + cnt[X] <= 128)) {
                    run += cnt[X]; ++X;
                }
                if (run > 0) {
                    S.a[ns] = ((unsigned)iy << 16) | ((unsigned)X0 << 8) | (unsigned)X;
                    S.b[ns] = ((unsigned)0 << 25) | ((unsigned)D << 19) | (unsigned)run;
                    ++ns;
                }
            }
        }
    }
    S.n = ns;
    return S;
}
constexpr SegTable g_raw = make_segs();

constexpr SegTable reorder_segs() {                  // heavy-first, 2 passes
    SegTable R{};
    int pos = 0;
    for (int i = 0; i < g_raw.n; ++i)
        if ((int)(g_raw.b[i] & 0x7FFFF) >= 120) { R.a[pos] = g_raw.a[i]; R.b[pos] = g_raw.b[i]; ++pos; }
    for (int i = 0; i < g_raw.n; ++i)
        if ((int)(g_raw.b[i] & 0x7FFFF) <  120) { R.a[pos] = g_raw.a[i]; R.b[pos] = g_raw.b[i]; ++pos; }
    R.n = pos;
    return R;
}
constexpr SegTable g_ct = reorder_segs();
constexpr int NSEG = g_ct.n;
static_assert(NSEG > 0 && NSEG <= 4096, "seg table overflow");
__device__ const SegTable g_segs = g_ct;

// ---------------------------------------------------------------- constexpr meta
// meta: split<<31 | start<<10 | ngroups. Wave dg's entries live at
// glist[start + dg*ng*4 .. +ng*4). Cheap prefix pass (~20K constexpr steps).
struct Meta { unsigned m[4096]; int ne; };
constexpr Meta make_meta() {
    Meta M{};
    int pos = 0;
    for (int i = 0; i < NSEG; ++i) {
        int cnt = (int)(g_ct.b[i] & 0x7FFFF);
        int ng = (((cnt + 1) >> 1) + 3) >> 2;        // groups of 4 per wave
        M.m[i] = (g_ct.b[i] & 0x80000000u) | ((unsigned)pos << 10) | (unsigned)ng;
        pos += 2 * ng * 4;
    }
    M.ne = pos;
    return M;
}
constexpr Meta g_mt = make_meta();
constexpr int NE_TOT = g_mt.ne;
static_assert(NE_TOT < (1 << 21), "start field overflow");
struct MetaArr { unsigned m[4096]; };
constexpr MetaArr make_meta_arr() { MetaArr A{}; for (int i = 0; i < 4096; ++i) A.m[i] = g_mt.m[i]; return A; }
__device__ const MetaArr g_metaD = make_meta_arr();

// entry: flush<<31 | bl<<19 | d<<12 | hw  (bl=16 -> LDS trash row; dummies pad
// each wave's list to a multiple of 4). Built on device each launch.
__device__ __align__(16) unsigned g_glist[NE_TOT + 64];

// ---------------------------------------------------------------- D1: mega
constexpr int SMAX_BLOCKS  = NCOLS / 256;           // 66
constexpr int BUILD_BLOCKS = (NSEG + 3) / 4;        // one WAVE per segment
constexpr int PACK_BLOCKS  = (C / 8) * (HW / 32);   // 1408
constexpr int ZERO_TOTAL   = C * NBINS / 4;         // 500000 f4
constexpr int ZERO_BLOCKS  = (ZERO_TOTAL + 1023) / 1024;  // 489
constexpr int MEGA_BLOCKS  = SMAX_BLOCKS + BUILD_BLOCKS + PACK_BLOCKS + ZERO_BLOCKS;

__global__ void __launch_bounds__(256) mega_kernel(
        const float* __restrict__ feat,     // [NCAM][C][HW]
        const float* __restrict__ logits,   // [NCAM][D][HW]
        float* __restrict__ probs_t,
        unsigned short* __restrict__ feat_p,   // [hw][c][6] bf16
        float* __restrict__ out) {
    __shared__ __align__(16) float tile[NCAM * 8 * 37];
    int b = blockIdx.x, t = threadIdx.x;

    if (b < SMAX_BLOCKS) {
        // -------- softmax over D, 1.5-pass streaming.
        int col = b * 256 + t;                       // < NCOLS exact
        int n  = col / HW;
        int hw = col - n * HW;
        const float* src = logits + ((size_t)n * D) * HW + hw;
        float m = -3.402823466e+38f;
#pragma unroll 20
        for (int d = 0; d < D; ++d)
            m = fmaxf(m, src[(size_t)d * HW]);
        float s = 0.f;
#pragma unroll 8
        for (int d = 0; d < D; ++d)
            s += expf(src[(size_t)d * HW] - m);
        float inv = 1.0f / s;
#pragma unroll 8
        for (int d = 0; d < D; ++d)
            probs_t[(size_t)((d << 12) | hw) * 8 + n] =
                expf(src[(size_t)d * HW] - m) * inv;

    } else if (b < SMAX_BLOCKS + BUILD_BLOCKS) {
        // -------- point-list build: one wave per segment, lane = depth cell.
        int slot = (b - SMAX_BLOCKS) * 4 + (t >> 6);
        int lane = t & 63;
        if (slot < NSEG) {
            unsigned da = g_segs.a[slot], db = g_segs.b[slot], mb = g_metaD.m[slot];
            int iy = (int)(da >> 16), X0 = (int)((da >> 8) & 0xFF), X1 = (int)(da & 0xFF);
            int d0 = (int)((db >> 25) & 0x3F), d1 = (int)((db >> 19) & 0x3F);
            int drange = d1 - d0;                    // <= 40 <= 64 lanes
            int ng4 = (int)(mb & 0x3FFu) * 4;
            unsigned* gl = g_glist + ((mb >> 10) & 0x1FFFFFu);
            int base = 0;
            for (int bl = 0; bl < X1 - X0; ++bl) {   // all cells of bl in ONE pass
                int d = d0 + lane;
                int hb = 0, he = 0, wb = 0, we = 0, cnt = 0;
                if (lane < drange) {
                    hb = g_tab.YP[d][iy];      he = g_tab.YP[d][iy + 1];
                    wb = g_tab.XP[d][X0 + bl]; we = g_tab.XP[d][X0 + bl + 1];
                    cnt = (he - hb) * (we - wb);
                }
                int inc = cnt;                       // inclusive wave scan
#pragma unroll
                for (int delta = 1; delta < 64; delta <<= 1) {
                    int y = __shfl_up(inc, delta, 64);
                    if (lane >= delta) inc += y;
                }
                int tot = __shfl(inc, 63, 64);
                int o = base + inc - cnt;            // this lane's first ordinal
                int run_end = base + tot;            // end of this bl-run
                for (int h = hb; h < he; ++h)
                    for (int w = wb; w < we; ++w) {
                        unsigned v = ((unsigned)bl << 19) | ((unsigned)d << 12)
                                   | (unsigned)(h * W + w);
                        // last two ordinals of the run == last-per-parity -> flush
                        if (o >= run_end - 2) v |= 0x80000000u;
                        gl[(o & 1) * ng4 + (o >> 1)] = v;
                        ++o;
                    }
                base = run_end;
            }
            int m = base;                            // pad with trash-row dummies
#pragma unroll
            for (int dg = 0; dg < 2; ++dg) {
                int cnt2 = (m + 1 - dg) >> 1;
                for (int k = cnt2 + lane; k < ng4; k += 64)
                    gl[dg * ng4 + k] = (16u << 19) | 0x80000000u;
            }
        }

    } else if (b < SMAX_BLOCKS + BUILD_BLOCKS + PACK_BLOCKS) {
        int bb = b - SMAX_BLOCKS - BUILD_BLOCKS;
        int c0  = (bb / 88) * 8;
        int hw0 = (bb % 88) * 32;
        int cq = t >> 5, hwL = t & 31;
#pragma unroll
        for (int n = 0; n < NCAM; ++n)
            tile[(n * 8 + cq) * 37 + hwL] =
                feat[((size_t)(n * C + c0 + cq)) * HW + hw0 + hwL];
        __syncthreads();
        int hl = t >> 3, cL = t & 7;
        unsigned short v[6];
#pragma unroll
        for (int n = 0; n < NCAM; ++n)
            v[n] = f2bf(tile[(n * 8 + cL) * 37 + hl]);
        // 12B store as 3 dwords (4B-aligned always: (hw*128+c)*12 % 4 == 0)
        unsigned* dst = (unsigned*)(feat_p +
            ((size_t)(hw0 + hl) * C + (c0 + cL)) * 6);
        dst[0] = (unsigned)v[0] | ((unsigned)v[1] << 16);
        dst[1] = (unsigned)v[2] | ((unsigned)v[3] << 16);
        dst[2] = (unsigned)v[4] | ((unsigned)v[5] << 16);

    } else {
        int base = (b - SMAX_BLOCKS - BUILD_BLOCKS - PACK_BLOCKS) * 1024;
#pragma unroll
        for (int k = 0; k < 4; ++k) {
            int i = base + k * 256 + t;
            if (i < ZERO_TOTAL) ((f4*)out)[i] = f4{0.f, 0.f, 0.f, 0.f};
        }
    }
}

// ---------------------------------------------------------------- D2: gather
// Grid = NSEG*2, 128 thr = 2 waves (one per dgroup); lane = channel within
// chalf. Entries preloaded to LDS (lgkm domain). Depth-3 unconditional
// pipeline (A/B/C slots, ~60 loads in flight/wave); uniform flush branch.
// Overshoot ISSUEs read garbage entries -> addresses stay inside ws (safe),
// never consumed.
__global__ void __launch_bounds__(128, 2) gather_kernel(
        const unsigned short* __restrict__ feat_p,   // [hw][c][6] bf16
        const float* __restrict__ probs_t,           // [(d<<12)|hw][8] f32
        float* __restrict__ out) {                   // [C][NBINS]
    __shared__ __align__(16) float T[2][17][66];     // 8976 B, row 16 = trash
    __shared__ __align__(16) unsigned EL[192];       // entry list (<=176 used)
    int t = threadIdx.x;
    int slot = blockIdx.x >> 1, chalf = blockIdx.x & 1;
    unsigned da = g_segs.a[slot], mb = g_metaD.m[slot];
    int iy = (int)(da >> 16), X0 = (int)((da >> 8) & 0xFF), X1 = (int)(da & 0xFF);
    int width = X1 - X0;
    bool split = (mb >> 31) != 0;
    int ng = (int)(mb & 0x3FFu);
    unsigned start = (mb >> 10) & 0x1FFFFFu;
    int dg = __builtin_amdgcn_readfirstlane((int)(threadIdx.x >> 6));
    int lane = t & 63;
    int c = chalf * 64 + lane;
    int ntot = ng * 8;                               // both waves' entry words

    if (t < ntot) EL[t] = g_glist[start + (unsigned)t];          // <=176
    if (t + 128 < ntot) EL[t + 128] = g_glist[start + (unsigned)(t + 128)];
    { float* Tf = &T[0][0][0];
      for (int i = t; i < 2 * 17 * 66; i += 128) Tf[i] = 0.f; }
    __syncthreads();

    const unsigned* ep = EL + dg * ng * 4;           // LDS pointer, 16B aligned
    const char* fbase = (const char*)feat_p + (size_t)c * 12;
    float* Tp = &T[dg][0][0];
    float racc = 0.f;

#define LOADE(E, g_) { uint4 ee_ = *(const uint4*)(ep + 4 * (g_));            \
    E[0] = (unsigned)__builtin_amdgcn_readfirstlane((int)ee_.x);              \
    E[1] = (unsigned)__builtin_amdgcn_readfirstlane((int)ee_.y);              \
    E[2] = (unsigned)__builtin_amdgcn_readfirstlane((int)ee_.z);              \
    E[3] = (unsigned)__builtin_amdgcn_readfirstlane((int)ee_.w); }
#define ISSUE(S, E) _Pragma("unroll") for (int i_ = 0; i_ < 4; ++i_) {        \
    const unsigned* fp_ = (const unsigned*)(fbase +                           \
                          (size_t)(E[i_] & 0xFFFu) * 1536);                   \
    fv##S[i_][0] = fp_[0]; fv##S[i_][1] = fp_[1]; fv##S[i_][2] = fp_[2];      \
    const float* pp_ = probs_t + ((size_t)(E[i_] & 0x3FFFFu) << 3);           \
    pa##S[i_] = *(const f4*)pp_; pb##S[i_] = *(const f2*)(pp_ + 4); }
#define CONS(S, E) _Pragma("unroll") for (int i_ = 0; i_ < 4; ++i_) {         \
    unsigned u0_ = fv##S[i_][0], u1_ = fv##S[i_][1], u2_ = fv##S[i_][2];      \
    racc += pa##S[i_].x * __uint_as_float(u0_ << 16)                          \
          + pa##S[i_].y * __uint_as_float(u0_ & 0xFFFF0000u)                  \
          + pa##S[i_].z * __uint_as_float(u1_ << 16)                          \
          + pa##S[i_].w * __uint_as_float(u1_ & 0xFFFF0000u)                  \
          + pb##S[i_].x * __uint_as_float(u2_ << 16)                          \
          + pb##S[i_].y * __uint_as_float(u2_ & 0xFFFF0000u);                 \
    if (E[i_] & 0x80000000u) {                                                \
        Tp[((E[i_] >> 19) & 31u) * 66 + (unsigned)lane] += racc; racc = 0.f; } }

    unsigned EA[4], EB[4], EC[4];
    unsigned fvA[4][3], fvB[4][3], fvC[4][3];
    f4 paA[4], paB[4], paC[4];
    f2 pbA[4], pbB[4], pbC[4];
    LOADE(EA, 0); ISSUE(A, EA);
    LOADE(EB, 1); ISSUE(B, EB);
    LOADE(EC, 2);
    int g = 0;
    for (; g + 3 <= ng; g += 3) {
        ISSUE(C, EC);                                // group g+2 data
        CONS(A, EA);                                 // group g
        LOADE(EA, g + 3); ISSUE(A, EA);              // group g+3 (==ng: garbage-safe)
        CONS(B, EB);                                 // group g+1
        LOADE(EB, g + 4); ISSUE(B, EB);              // group g+4 (overshoot-safe)
        CONS(C, EC);                                 // group g+2
        LOADE(EC, g + 5);                            // EL idx <= 8ng+11 <= 187 < 192
    }
    if (g + 2 < ng) ISSUE(C, EC);                    // (dead by algebra; kept for safety)
    if (g     < ng) CONS(A, EA);
    if (g + 1 < ng) CONS(B, EB);
    if (g + 2 < ng) CONS(C, EC);
#undef LOADE
#undef ISSUE
#undef CONS
    __syncthreads();

    int binbase = iy * BEV + X0;
#pragma unroll
    for (int it = 0; it < 8; ++it) {                 // 16 bl x 8 cc per iter
        int bl = t & 15, cc = it * 8 + (t >> 4);     // cc in [0,64)
        if (bl < width) {
            float v = T[0][bl][cc] + T[1][bl][cc];
            float* dst = &out[(size_t)(chalf * 64 + cc) * NBINS + binbase + bl];
            if (split) atomicAdd(dst, v);
            else       *dst = v;
        }
    }
}

// ---------------------------------------------------------------- launch
extern "C" void kernel_launch(void* const* d_in, const int* in_sizes, int n_in,
                              void* d_out, int out_size, void* d_ws, size_t ws_size,
                              hipStream_t stream) {
    const float* img_feat     = (const float*)d_in[0];
    const float* depth_logits = (const float*)d_in[1];
    float* out = (float*)d_out;

    char* p = (char*)d_ws;
    float*          probs_t = (float*)p;          p += (size_t)D * 4096 * 8 * 4;  // 5.24 MB
    unsigned short* feat_p  = (unsigned short*)p; p += (size_t)HW * C * 6 * 2;    // 4.33 MB

    mega_kernel<<<MEGA_BLOCKS, 256, 0, stream>>>(
        img_feat, depth_logits, probs_t, feat_p, out);
    gather_kernel<<<NSEG * 2, 128, 0, stream>>>(feat_p, probs_t, out);
}

// Round 8
// 103.772 us; speedup vs baseline: 1.0392x; 1.0239x over previous
//
#include <hip/hip_runtime.h>

// R18: budget re-fit (R10 exact: 124.5=44.5fill+26mega+49gather+5ovh) puts
// current split at mega~38, gather~15. R17's inner-loop opts were weak ->
// per-block/branch fixed costs dominate. Two mechanism fixes:
//  1) smax probs writes were 32B-stride 4B scatters (~8x sector write
//     amplification, 16 txn/store). New smax: block = 6 cams x 42 hw, all
//     n in-block; pass-3 streams d in chunks of 8 through an LDS transpose
//     and writes each (d,hw) cell's 6 probs as dense f4+f2 (24B contig per
//     thread). Same math order (bitwise-identical), same probs layout ->
//     gather read side untouched.
//  2) gather: merge both chalves into one 256-thr block (4 waves = dg x
//     chalf, grid = NSEG): EL/glist staged once, decode/sync/zero
//     amortized, probs loads L1-shared. Pipeline macros unchanged (R17).
// Predict: mega -> ~31-33, gather -> ~12-13, total -> ~97-101.
// Neutral => smax-writes exonerated; next: constexpr-chunked glist to
// delete the build branch.

constexpr int D = 40, H = 32, W = 88, HW = H * W;       // 2816
constexpr int C = 128, NCAM = 6;
constexpr int BEV = 125, NBINS = BEV * BEV;             // 15625
constexpr int NCOLS = NCAM * HW;                        // 16896

typedef __attribute__((ext_vector_type(8))) unsigned short us8;
typedef __attribute__((ext_vector_type(4))) float f4;
typedef __attribute__((ext_vector_type(2))) float f2;

__device__ __forceinline__ unsigned short f2bf(float x) {   // RNE
    unsigned u = __float_as_uint(x);
    return (unsigned short)((u + 0x7FFF + ((u >> 16) & 1)) >> 16);
}

// ---------------------------------------------------------------- constexpr tables
struct Tabs { short XP[D][126]; short YP[D][126]; };
constexpr Tabs make_tabs() {
    Tabs t{};
    for (int d = 0; d < D; ++d) {
        int dep = d + 2;
        int cntx[126] = {};
        for (int w = 0; w < W; ++w) {
            float gx = (float)(w * dep) / 3567.0f * 100.0f - 50.0f;
            int ix = (int)((gx + 50.0f) / 0.8f);
            if (ix < 125) cntx[ix]++;
        }
        t.XP[d][0] = 0;
        for (int X = 0; X < 125; ++X) t.XP[d][X + 1] = (short)(t.XP[d][X] + cntx[X]);
        int cnty[126] = {};
        for (int h = 0; h < H; ++h) {
            float gy = (float)(h * dep) / 1271.0f * 100.0f - 50.0f;
            int iy = (int)((gy + 50.0f) / 0.8f);
            if (iy < 125) cnty[iy]++;
        }
        t.YP[d][0] = 0;
        for (int Y = 0; Y < 125; ++Y) t.YP[d][Y + 1] = (short)(t.YP[d][Y] + cnty[Y]);
    }
    return t;
}
constexpr Tabs g_tabs = make_tabs();
__device__ const Tabs g_tab = g_tabs;                // device copy for build

// ---------------------------------------------------------------- constexpr segments
// a: iy<<16 | X0<<8 | X1 ; b(raw): split<<31 | d0<<25 | d1<<19 | count
struct SegTable { unsigned a[4096]; unsigned b[4096]; int n; };

constexpr SegTable make_segs() {
    SegTable S{};
    int ns = 0;
    for (int iy = 0; iy < 125; ++iy) {
        int cnt[125] = {};
        for (int d = 0; d < D; ++d) {
            int yc = g_tabs.YP[d][iy + 1] - g_tabs.YP[d][iy];
            if (yc == 0) continue;
            for (int X = 0; X < 125; ++X)
                cnt[X] += (g_tabs.XP[d][X + 1] - g_tabs.XP[d][X]) * yc;
        }
        int X = 0;
        while (X < 125) {
            if (cnt[X] > 176) {                      // lone heavy bin: d-split
                int d0 = 0;
                while (d0 < D) {
                    int run = 0, d1 = d0;
                    while (d1 < D) {
                        int piece = (g_tabs.XP[d1][X + 1] - g_tabs.XP[d1][X]) *
                                    (g_tabs.YP[d1][iy + 1] - g_tabs.YP[d1][iy]);
                        if (d1 > d0 && run + piece > 128) break;
                        run += piece; ++d1;
                    }
                    if (run > 0) {
                        S.a[ns] = ((unsigned)iy << 16) | ((unsigned)X << 8) | (unsigned)(X + 1);
                        S.b[ns] = (1u << 31) | ((unsigned)d0 << 25) | ((unsigned)d1 << 19) | (unsigned)run;
                        ++ns;
                    }
                    d0 = d1;
                }
                ++X;
            } else {
                int X0 = X, run = 0;
                while (X < 125 && (X - X0) < 16 && cnt[X] <= 176 &&
                       (X == X0 || run + cnt[X] <= 128)) {
                    run += cnt[X]; ++X;
                }
                if (run > 0) {
                    S.a[ns] = ((unsigned)iy << 16) | ((unsigned)X0 << 8) | (unsigned)X;
                    S.b[ns] = ((unsigned)0 << 25) | ((unsigned)D << 19) | (unsigned)run;
                    ++ns;
                }
            }
        }
    }
    S.n = ns;
    return S;
}
constexpr SegTable g_raw = make_segs();

constexpr SegTable reorder_segs() {                  // heavy-first, 2 passes
    SegTable R{};
    int pos = 0;
    for (int i = 0; i < g_raw.n; ++i)
        if ((int)(g_raw.b[i] & 0x7FFFF) >= 120) { R.a[pos] = g_raw.a[i]; R.b[pos] = g_raw.b[i]; ++pos; }
    for (int i = 0; i < g_raw.n; ++i)
        if ((int)(g_raw.b[i] & 0x7FFFF) <  120) { R.a[pos] = g_raw.a[i]; R.b[pos] = g_raw.b[i]; ++pos; }
    R.n = pos;
    return R;
}
constexpr SegTable g_ct = reorder_segs();
constexpr int NSEG = g_ct.n;
static_assert(NSEG > 0 && NSEG <= 4096, "seg table overflow");
__device__ const SegTable g_segs = g_ct;

// ---------------------------------------------------------------- constexpr meta
// meta: split<<31 | start<<10 | ngroups. Wave dg's entries live at
// glist[start + dg*ng*4 .. +ng*4). Cheap prefix pass (~20K constexpr steps).
struct Meta { unsigned m[4096]; int ne; };
constexpr Meta make_meta() {
    Meta M{};
    int pos = 0;
    for (int i = 0; i < NSEG; ++i) {
        int cnt = (int)(g_ct.b[i] & 0x7FFFF);
        int ng = (((cnt + 1) >> 1) + 3) >> 2;        // groups of 4 per wave
        M.m[i] = (g_ct.b[i] & 0x80000000u) | ((unsigned)pos << 10) | (unsigned)ng;
        pos += 2 * ng * 4;
    }
    M.ne = pos;
    return M;
}
constexpr Meta g_mt = make_meta();
constexpr int NE_TOT = g_mt.ne;
static_assert(NE_TOT < (1 << 21), "start field overflow");
struct MetaArr { unsigned m[4096]; };
constexpr MetaArr make_meta_arr() { MetaArr A{}; for (int i = 0; i < 4096; ++i) A.m[i] = g_mt.m[i]; return A; }
__device__ const MetaArr g_metaD = make_meta_arr();

// entry: flush<<31 | bl<<19 | d<<12 | hw  (bl=16 -> LDS trash row; dummies pad
// each wave's list to a multiple of 4). Built on device each launch.
__device__ __align__(16) unsigned g_glist[NE_TOT + 64];

// ---------------------------------------------------------------- D1: mega
constexpr int SMAX_HWT    = 42;                     // hw per smax block
constexpr int SMAX_BLOCKS = (HW + SMAX_HWT - 1) / SMAX_HWT;   // 68
constexpr int BUILD_BLOCKS = (NSEG + 3) / 4;        // one WAVE per segment
constexpr int PACK_BLOCKS  = (C / 8) * (HW / 32);   // 1408
constexpr int ZERO_TOTAL   = C * NBINS / 4;         // 500000 f4
constexpr int ZERO_BLOCKS  = (ZERO_TOTAL + 1023) / 1024;  // 489
constexpr int MEGA_BLOCKS  = BUILD_BLOCKS + SMAX_BLOCKS + PACK_BLOCKS + ZERO_BLOCKS;

__global__ void __launch_bounds__(256) mega_kernel(
        const float* __restrict__ feat,     // [NCAM][C][HW]
        const float* __restrict__ logits,   // [NCAM][D][HW]
        float* __restrict__ probs_t,
        unsigned short* __restrict__ feat_p,   // [hw][c][6] bf16
        float* __restrict__ out) {
    __shared__ __align__(16) float shmem[2016];      // pack tile(1776) / smax ps(2016)
    int b = blockIdx.x, t = threadIdx.x;

    if (b < BUILD_BLOCKS) {
        // -------- point-list build: one wave per segment, lane = depth cell.
        int slot = b * 4 + (t >> 6);
        int lane = t & 63;
        if (slot < NSEG) {
            unsigned da = g_segs.a[slot], db = g_segs.b[slot], mb = g_metaD.m[slot];
            int iy = (int)(da >> 16), X0 = (int)((da >> 8) & 0xFF), X1 = (int)(da & 0xFF);
            int d0 = (int)((db >> 25) & 0x3F), d1 = (int)((db >> 19) & 0x3F);
            int drange = d1 - d0;                    // <= 40 <= 64 lanes
            int ng4 = (int)(mb & 0x3FFu) * 4;
            unsigned* gl = g_glist + ((mb >> 10) & 0x1FFFFFu);
            int base = 0;
            for (int bl = 0; bl < X1 - X0; ++bl) {   // all cells of bl in ONE pass
                int d = d0 + lane;
                int hb = 0, he = 0, wb = 0, we = 0, cnt = 0;
                if (lane < drange) {
                    hb = g_tab.YP[d][iy];      he = g_tab.YP[d][iy + 1];
                    wb = g_tab.XP[d][X0 + bl]; we = g_tab.XP[d][X0 + bl + 1];
                    cnt = (he - hb) * (we - wb);
                }
                int inc = cnt;                       // inclusive wave scan
#pragma unroll
                for (int delta = 1; delta < 64; delta <<= 1) {
                    int y = __shfl_up(inc, delta, 64);
                    if (lane >= delta) inc += y;
                }
                int tot = __shfl(inc, 63, 64);
                int o = base + inc - cnt;            // this lane's first ordinal
                int run_end = base + tot;            // end of this bl-run
                for (int h = hb; h < he; ++h)
                    for (int w = wb; w < we; ++w) {
                        unsigned v = ((unsigned)bl << 19) | ((unsigned)d << 12)
                                   | (unsigned)(h * W + w);
                        // last two ordinals of the run == last-per-parity -> flush
                        if (o >= run_end - 2) v |= 0x80000000u;
                        gl[(o & 1) * ng4 + (o >> 1)] = v;
                        ++o;
                    }
                base = run_end;
            }
            int m = base;                            // pad with trash-row dummies
#pragma unroll
            for (int dg = 0; dg < 2; ++dg) {
                int cnt2 = (m + 1 - dg) >> 1;
                for (int k = cnt2 + lane; k < ng4; k += 64)
                    gl[dg * ng4 + k] = (16u << 19) | 0x80000000u;
            }
        }

    } else if (b < BUILD_BLOCKS + SMAX_BLOCKS) {
        // -------- softmax over D. Block = 6 cams x 42 hw; pass-3 streams d
        // in chunks of 8 through LDS; dense 24B/cell writes (no scatter).
        int hw0 = (b - BUILD_BLOCKS) * SMAX_HWT;
        int n   = t / SMAX_HWT;                      // 0..6 (6 = inactive)
        int hwL = t - n * SMAX_HWT;
        int hw  = hw0 + hwL;
        bool act = (n < NCAM) && (hw < HW);
        const float* src = logits + ((size_t)n * D) * HW + hw;
        float m = -3.402823466e+38f, inv = 0.f;
        if (act) {
#pragma unroll 20
            for (int d = 0; d < D; ++d)
                m = fmaxf(m, src[(size_t)d * HW]);
            float s = 0.f;
#pragma unroll 8
            for (int d = 0; d < D; ++d)
                s += expf(src[(size_t)d * HW] - m);
            inv = 1.0f / s;
        }
        for (int dc = 0; dc < D; dc += 8) {          // 5 chunks
            if (act) {
#pragma unroll
                for (int j = 0; j < 8; ++j)
                    shmem[(j * NCAM + n) * SMAX_HWT + hwL] =
                        expf(src[(size_t)(dc + j) * HW] - m) * inv;
            }
            __syncthreads();
            for (int cell = t; cell < 8 * SMAX_HWT; cell += 256) {
                int j = cell / SMAX_HWT, hl = cell - j * SMAX_HWT;
                if (hw0 + hl < HW) {
                    const float* ps = &shmem[(j * NCAM) * SMAX_HWT + hl];
                    f4 lo = { ps[0], ps[SMAX_HWT], ps[2 * SMAX_HWT], ps[3 * SMAX_HWT] };
                    f2 hi = { ps[4 * SMAX_HWT], ps[5 * SMAX_HWT] };
                    float* dst = probs_t +
                        ((size_t)(((dc + j) << 12) | (hw0 + hl)) << 3);
                    *(f4*)dst = lo;
                    *(f2*)(dst + 4) = hi;
                }
            }
            __syncthreads();
        }

    } else if (b < BUILD_BLOCKS + SMAX_BLOCKS + PACK_BLOCKS) {
        float* tile = shmem;                         // [NCAM*8][37]
        int bb = b - BUILD_BLOCKS - SMAX_BLOCKS;
        int c0  = (bb / 88) * 8;
        int hw0 = (bb % 88) * 32;
        int cq = t >> 5, hwL = t & 31;
#pragma unroll
        for (int n2 = 0; n2 < NCAM; ++n2)
            tile[(n2 * 8 + cq) * 37 + hwL] =
                feat[((size_t)(n2 * C + c0 + cq)) * HW + hw0 + hwL];
        __syncthreads();
        int hl = t >> 3, cL = t & 7;
        unsigned short v[6];
#pragma unroll
        for (int n2 = 0; n2 < NCAM; ++n2)
            v[n2] = f2bf(tile[(n2 * 8 + cL) * 37 + hl]);
        // 12B store as 3 dwords (4B-aligned always)
        unsigned* dst = (unsigned*)(feat_p +
            ((size_t)(hw0 + hl) * C + (c0 + cL)) * 6);
        dst[0] = (unsigned)v[0] | ((unsigned)v[1] << 16);
        dst[1] = (unsigned)v[2] | ((unsigned)v[3] << 16);
        dst[2] = (unsigned)v[4] | ((unsigned)v[5] << 16);

    } else {
        int base = (b - BUILD_BLOCKS - SMAX_BLOCKS - PACK_BLOCKS) * 1024;
#pragma unroll
        for (int k = 0; k < 4; ++k) {
            int i = base + k * 256 + t;
            if (i < ZERO_TOTAL) ((f4*)out)[i] = f4{0.f, 0.f, 0.f, 0.f};
        }
    }
}

// ---------------------------------------------------------------- D2: gather
// Grid = NSEG, 256 thr = 4 waves (dg x chalf); lane = channel within chalf.
// Entries staged once to LDS; depth-3 unconditional pipeline per wave.
__global__ void __launch_bounds__(256, 2) gather_kernel(
        const unsigned short* __restrict__ feat_p,   // [hw][c][6] bf16
        const float* __restrict__ probs_t,           // [(d<<12)|hw][8] f32
        float* __restrict__ out) {                   // [C][NBINS]
    __shared__ __align__(16) float T[2][2][17][66];  // [dg][chalf], row16=trash
    __shared__ __align__(16) unsigned EL[192];       // entry list (<=176 used)
    int t = threadIdx.x;
    int slot = blockIdx.x;
    unsigned da = g_segs.a[slot], mb = g_metaD.m[slot];
    int iy = (int)(da >> 16), X0 = (int)((da >> 8) & 0xFF), X1 = (int)(da & 0xFF);
    int width = X1 - X0;
    bool split = (mb >> 31) != 0;
    int ng = (int)(mb & 0x3FFu);
    unsigned start = (mb >> 10) & 0x1FFFFFu;
    int wave  = __builtin_amdgcn_readfirstlane((int)(threadIdx.x >> 6));
    int dg    = wave & 1;
    int chalf = wave >> 1;
    int lane = t & 63;
    int c = chalf * 64 + lane;
    int ntot = ng * 8;                               // both dgroups' words

    if (t < ntot) EL[t] = g_glist[start + (unsigned)t];          // <=176
    { float* Tf = &T[0][0][0][0];
      for (int i = t; i < 2 * 2 * 17 * 66; i += 256) Tf[i] = 0.f; }
    __syncthreads();

    const unsigned* ep = EL + dg * ng * 4;           // LDS pointer, 16B aligned
    const char* fbase = (const char*)feat_p + (size_t)c * 12;
    float* Tp = &T[dg][chalf][0][0];
    float racc = 0.f;

#define LOADE(E, g_) { uint4 ee_ = *(const uint4*)(ep + 4 * (g_));            \
    E[0] = (unsigned)__builtin_amdgcn_readfirstlane((int)ee_.x);              \
    E[1] = (unsigned)__builtin_amdgcn_readfirstlane((int)ee_.y);              \
    E[2] = (unsigned)__builtin_amdgcn_readfirstlane((int)ee_.z);              \
    E[3] = (unsigned)__builtin_amdgcn_readfirstlane((int)ee_.w); }
#define ISSUE(S, E) _Pragma("unroll") for (int i_ = 0; i_ < 4; ++i_) {        \
    const unsigned* fp_ = (const unsigned*)(fbase +                           \
                          (size_t)(E[i_] & 0xFFFu) * 1536);                   \
    fv##S[i_][0] = fp_[0]; fv##S[i_][1] = fp_[1]; fv##S[i_][2] = fp_[2];      \
    const float* pp_ = probs_t + ((size_t)(E[i_] & 0x3FFFFu) << 3);           \
    pa##S[i_] = *(const f4*)pp_; pb##S[i_] = *(const f2*)(pp_ + 4); }
#define CONS(S, E) _Pragma("unroll") for (int i_ = 0; i_ < 4; ++i_) {         \
    unsigned u0_ = fv##S[i_][0], u1_ = fv##S[i_][1], u2_ = fv##S[i_][2];      \
    racc += pa##S[i_].x * __uint_as_float(u0_ << 16)                          \
          + pa##S[i_].y * __uint_as_float(u0_ & 0xFFFF0000u)                  \
          + pa##S[i_].z * __uint_as_float(u1_ << 16)                          \
          + pa##S[i_].w * __uint_as_float(u1_ & 0xFFFF0000u)                  \
          + pb##S[i_].x * __uint_as_float(u2_ << 16)                          \
          + pb##S[i_].y * __uint_as_float(u2_ & 0xFFFF0000u);                 \
    if (E[i_] & 0x80000000u) {                                                \
        Tp[((E[i_] >> 19) & 31u) * 66 + (unsigned)lane] += racc; racc = 0.f; } }

    unsigned EA[4], EB[4], EC[4];
    unsigned fvA[4][3], fvB[4][3], fvC[4][3];
    f4 paA[4], paB[4], paC[4];
    f2 pbA[4], pbB[4], pbC[4];
    LOADE(EA, 0); ISSUE(A, EA);
    LOADE(EB, 1); ISSUE(B, EB);
    LOADE(EC, 2);
    int g = 0;
    for (; g + 3 <= ng; g += 3) {
        ISSUE(C, EC);                                // group g+2 data
        CONS(A, EA);                                 // group g
        LOADE(EA, g + 3); ISSUE(A, EA);              // group g+3 (overshoot-safe)
        CONS(B, EB);                                 // group g+1
        LOADE(EB, g + 4); ISSUE(B, EB);              // group g+4 (overshoot-safe)
        CONS(C, EC);                                 // group g+2
        LOADE(EC, g + 5);                            // EL idx <= 8ng+11 <= 187 < 192
    }
    if (g + 2 < ng) ISSUE(C, EC);                    // (dead by algebra; safety)
    if (g     < ng) CONS(A, EA);
    if (g + 1 < ng) CONS(B, EB);
    if (g + 2 < ng) CONS(C, EC);
#undef LOADE
#undef ISSUE
#undef CONS
    __syncthreads();

    int binbase = iy * BEV + X0;
#pragma unroll
    for (int it = 0; it < 8; ++it) {                 // 16 bl x 16 cc per iter
        int bl = t & 15, cc = it * 16 + (t >> 4);    // cc in [0,128)
        if (bl < width) {
            int ch = cc >> 6, cl = cc & 63;
            float v = T[0][ch][bl][cl] + T[1][ch][bl][cl];
            float* dst = &out[(size_t)cc * NBINS + binbase + bl];
            if (split) atomicAdd(dst, v);
            else       *dst = v;
        }
    }
}

// ---------------------------------------------------------------- launch
extern "C" void kernel_launch(void* const* d_in, const int* in_sizes, int n_in,
                              void* d_out, int out_size, void* d_ws, size_t ws_size,
                              hipStream_t stream) {
    const float* img_feat     = (const float*)d_in[0];
    const float* depth_logits = (const float*)d_in[1];
    float* out = (float*)d_out;

    char* p = (char*)d_ws;
    float*          probs_t = (float*)p;          p += (size_t)D * 4096 * 8 * 4;  // 5.24 MB
    unsigned short* feat_p  = (unsigned short*)p; p += (size_t)HW * C * 6 * 2;    // 4.33 MB

    mega_kernel<<<MEGA_BLOCKS, 256, 0, stream>>>(
        img_feat, depth_logits, probs_t, feat_p, out);
    gather_kernel<<<NSEG, 256, 0, stream>>>(feat_p, probs_t, out);
}